// Round 12
// baseline (320.670 us; speedup 1.0000x reference)
//
#include <hip/hip_runtime.h>

#define HD 64      // hidden/feature dim (D == H == 64)
#define PSUB 16    // partial slots per graph (pool accumulation spread)
#define NBLK 512   // histogram blocks (edge slices)
#define NBKT 512   // dst buckets (bucket = dst >> 7, 128 nodes each; N <= 65536)

// ---- bf16 helpers (manual, RNE) ----
__device__ __forceinline__ unsigned short f2bf(float f) {
    union { float f; unsigned u; } v; v.f = f;
    unsigned r = v.u + 0x7FFF + ((v.u >> 16) & 1);
    return (unsigned short)(r >> 16);
}
__device__ __forceinline__ float bf2f(unsigned short h) {
    union { unsigned u; float f; } v; v.u = ((unsigned)h) << 16;
    return v.f;
}
__device__ __forceinline__ int rdlane(int v, int l) {
    return __builtin_amdgcn_readlane(v, l);
}
__device__ __forceinline__ float rdlanef(float v, int l) {
    union { float f; int i; } u; u.f = v;
    u.i = __builtin_amdgcn_readlane(u.i, l);
    return u.f;
}

// ================= atomic-free bucketed CSR build =================

__global__ __launch_bounds__(256) void hist1_k(const int* __restrict__ dst,
                                               int* __restrict__ hist, int E, int chunk)
{
    __shared__ int lh[NBKT];
    int t = threadIdx.x;
    for (int i = t; i < NBKT; i += 256) lh[i] = 0;
    __syncthreads();
    int base = blockIdx.x * chunk;
    int end  = min(base + chunk, E);
    for (int i = base + t; i < end; i += 256)
        atomicAdd(&lh[dst[i] >> 7], 1);
    __syncthreads();
    for (int i = t; i < NBKT; i += 256)
        hist[blockIdx.x * NBKT + i] = lh[i];
}

// 2a) tile-reduce logical order l = bkt*NBLK + blk  (phys = blk*NBKT + bkt)
__global__ __launch_bounds__(256) void scanA_k(const int* __restrict__ hist,
                                               int* __restrict__ tsum)
{
    __shared__ int s[256];
    int t = threadIdx.x;
    int l = blockIdx.x * 256 + t;
    int phys = (l & (NBLK - 1)) * NBKT + (l >> 9);
    s[t] = hist[phys];
    __syncthreads();
    for (int off = 128; off > 0; off >>= 1) {
        if (t < off) s[t] += s[t + off];
        __syncthreads();
    }
    if (t == 0) tsum[blockIdx.x] = s[0];
}

__global__ __launch_bounds__(1024) void scanB_k(int* __restrict__ tsum, int nb)
{
    __shared__ int s[1024];
    int t = threadIdx.x;
    int v = (t < nb) ? tsum[t] : 0;
    s[t] = v;
    __syncthreads();
    for (int off = 1; off < 1024; off <<= 1) {
        int u = (t >= off) ? s[t - off] : 0;
        __syncthreads();
        s[t] += u;
        __syncthreads();
    }
    if (t < nb) tsum[t] = s[t] - v;
}

__global__ __launch_bounds__(256) void scanC_k(const int* __restrict__ hist,
                                               const int* __restrict__ tsum,
                                               int* __restrict__ scanned)
{
    __shared__ int s[256];
    int t = threadIdx.x;
    int l = blockIdx.x * 256 + t;
    int phys = (l & (NBLK - 1)) * NBKT + (l >> 9);
    int own = hist[phys];
    s[t] = own;
    __syncthreads();
    for (int off = 1; off < 256; off <<= 1) {
        int u = (t >= off) ? s[t - off] : 0;
        __syncthreads();
        s[t] += u;
        __syncthreads();
    }
    scanned[l] = tsum[blockIdx.x] + s[t] - own;
}

// 3) bucket-sorted append of packed (src<<7 | dst&127); per-block private ranges
__global__ __launch_bounds__(256) void append_k(const int* __restrict__ src,
    const int* __restrict__ dst, const int* __restrict__ scanned,
    int* __restrict__ pairs, int E, int chunk)
{
    __shared__ int cur[NBKT];
    int t = threadIdx.x;
    int blk = blockIdx.x;
    for (int i = t; i < NBKT; i += 256) cur[i] = scanned[i * NBLK + blk];
    __syncthreads();
    int base = blk * chunk;
    int end  = min(base + chunk, E);
    for (int i = base + t; i < end; i += 256) {
        int s = src[i], d = dst[i];
        int p = atomicAdd(&cur[d >> 7], 1);
        pairs[p] = (s << 7) | (d & 127);
    }
}

// 4) per-bucket: node counts -> offsets/dis, then in-bucket scatter of csr_src
__global__ __launch_bounds__(256) void bucket_csr_k(const int* __restrict__ pairs,
    const int* __restrict__ scanned, int* __restrict__ offsets,
    float* __restrict__ dis, int* __restrict__ csr_src, int N, int E)
{
    __shared__ int cnt[128];
    __shared__ int sc[128];
    __shared__ int cur[128];
    int t = threadIdx.x;
    int b = blockIdx.x;
    int nodeBase = b * 128;
    int nNodes = min(128, N - nodeBase);
    int bBase = scanned[b * NBLK];
    int bEnd  = (b + 1 < NBKT) ? scanned[(b + 1) * NBLK] : E;

    if (t < 128) cnt[t] = 0;
    __syncthreads();
    for (int i = bBase + t; i < bEnd; i += 256)
        atomicAdd(&cnt[pairs[i] & 127], 1);
    __syncthreads();
    int myc = (t < 128) ? cnt[t] : 0;
    if (t < 128) sc[t] = myc;
    __syncthreads();
    for (int off = 1; off < 128; off <<= 1) {
        int u = (t < 128 && t >= off) ? sc[t - off] : 0;
        __syncthreads();
        if (t < 128) sc[t] += u;
        __syncthreads();
    }
    if (t < 128) {
        int excl = sc[t] - myc;
        cur[t] = excl;
        if (t < nNodes) {
            offsets[nodeBase + t] = bBase + excl;
            dis[nodeBase + t] = rsqrtf(1.0f + (float)myc);
        }
    }
    if (t == 0 && b == gridDim.x - 1) offsets[N] = E;
    __syncthreads();
    for (int i = bBase + t; i < bEnd; i += 256) {
        int pk = pairs[i];
        int pos = bBase + atomicAdd(&cur[pk & 127], 1);
        csr_src[pos] = ((unsigned)pk) >> 7;
    }
}

// ================= layers =================

// register-tiled 64x64 GEMM, fp32 in, bf16 HALF-TABLE outputs:
// h0[r*32 + c] = channels 0..31, h1[r*32 + c] = channels 32..63.
__global__ __launch_bounds__(256) void gemm64_k(
    const float* __restrict__ in, const float* __restrict__ b_prev, int relu_prev,
    const float* __restrict__ W,
    unsigned short* __restrict__ h0, unsigned short* __restrict__ h1, int n)
{
    __shared__ float HsT[HD][68];
    __shared__ float Ws[HD][HD];
    int t = threadIdx.x;
    int rowBase = blockIdx.x * 64;

    for (int i = t; i < HD * HD / 4; i += 256)
        ((float4*)Ws)[i] = ((const float4*)W)[i];

    {
        int k0 = (t & 15) * 4;
        float4 bb = make_float4(0.f, 0.f, 0.f, 0.f);
        if (b_prev) bb = *(const float4*)&b_prev[k0];
        for (int it = 0; it < 4; ++it) {
            int r = (t >> 4) + it * 16;
            int row = rowBase + r;
            float4 v = make_float4(0.f, 0.f, 0.f, 0.f);
            if (row < n) {
                v = *(const float4*)&in[(size_t)row * HD + k0];
                v.x += bb.x; v.y += bb.y; v.z += bb.z; v.w += bb.w;
                if (relu_prev) {
                    v.x = fmaxf(v.x, 0.f); v.y = fmaxf(v.y, 0.f);
                    v.z = fmaxf(v.z, 0.f); v.w = fmaxf(v.w, 0.f);
                }
            }
            HsT[k0 + 0][r] = v.x;
            HsT[k0 + 1][r] = v.y;
            HsT[k0 + 2][r] = v.z;
            HsT[k0 + 3][r] = v.w;
        }
    }
    __syncthreads();

    int c4 = (t & 15) * 4;
    int r4 = (t >> 4) * 4;
    float acc[4][4];
    #pragma unroll
    for (int i = 0; i < 4; ++i)
        #pragma unroll
        for (int j = 0; j < 4; ++j) acc[i][j] = 0.f;

    #pragma unroll 8
    for (int k = 0; k < HD; ++k) {
        float4 a = *(const float4*)&HsT[k][r4];
        float4 b = *(const float4*)&Ws[k][c4];
        acc[0][0] += a.x * b.x; acc[0][1] += a.x * b.y; acc[0][2] += a.x * b.z; acc[0][3] += a.x * b.w;
        acc[1][0] += a.y * b.x; acc[1][1] += a.y * b.y; acc[1][2] += a.y * b.z; acc[1][3] += a.y * b.w;
        acc[2][0] += a.z * b.x; acc[2][1] += a.z * b.y; acc[2][2] += a.z * b.z; acc[2][3] += a.z * b.w;
        acc[3][0] += a.w * b.x; acc[3][1] += a.w * b.y; acc[3][2] += a.w * b.z; acc[3][3] += a.w * b.w;
    }

    unsigned short* tab = (c4 & 32) ? h1 : h0;
    int cc = c4 & 31;
    #pragma unroll
    for (int i = 0; i < 4; ++i) {
        int row = rowBase + r4 + i;
        if (row < n) {
            ushort4 o;
            o.x = f2bf(acc[i][0]); o.y = f2bf(acc[i][1]);
            o.z = f2bf(acc[i][2]); o.w = f2bf(acc[i][3]);
            *(ushort4*)&tab[(size_t)row * 32 + cc] = o;
        }
    }
}

// Channel-split CSR gather-aggregate: grid (nb, 2); pass h gathers only from the
// 3.2 MB half-table h (L2-resident). lane = (e = lane>>5 edge slot, c = lane&31).
// One gather instruction covers 2 edges x 32 ch; 8 gathers in flight per 16 edges.
// Quarters combined with shfl_xor(32); fp32 half-row written to agg.
__global__ __launch_bounds__(256) void agg_csr_k(
    const unsigned short* __restrict__ h0, const unsigned short* __restrict__ h1,
    const float* __restrict__ dis, const int* __restrict__ offsets,
    const int* __restrict__ csr_src, float* __restrict__ agg, int n)
{
    int wid  = (blockIdx.x * blockDim.x + threadIdx.x) >> 6;
    int lane = threadIdx.x & 63;
    if (wid >= n) return;
    int half = blockIdx.y;
    const unsigned short* __restrict__ tab = half ? h1 : h0;
    int c = lane & 31;
    int e = lane >> 5;
    float dn = dis[wid];

    float acc = 0.f;
    if (e == 0)  // self-loop counted once
        acc = dn * dn * bf2f(tab[(size_t)wid * 32 + c]);

    int beg = offsets[wid], end = offsets[wid + 1];
    for (int base = beg; base < end; base += 64) {
        int m = min(64, end - base);
        int idx = 0;
        float dv = 0.f;
        if (lane < m) {
            idx = csr_src[base + lane];
            dv  = dis[idx];
        }
        int lim = m - 1;
        for (int j = 0; j < m; j += 16) {
            int rw[8];
            float h[8];
            #pragma unroll
            for (int u = 0; u < 8; ++u) {
                int j2 = j + 2 * u;
                int s0 = rdlane(idx, min(j2, lim));
                int s1 = rdlane(idx, min(j2 + 1, lim));
                rw[u] = e ? s1 : s0;
            }
            #pragma unroll
            for (int u = 0; u < 8; ++u)
                h[u] = bf2f(tab[(size_t)rw[u] * 32 + c]);   // 8 gathers in flight
            #pragma unroll
            for (int u = 0; u < 8; ++u) {
                int j2 = j + 2 * u;
                float w0 = (j2     < m) ? rdlanef(dv, min(j2, lim))     : 0.f;
                float w1 = (j2 + 1 < m) ? rdlanef(dv, min(j2 + 1, lim)) : 0.f;
                float wgt = e ? w1 : w0;
                acc += dn * wgt * h[u];
            }
        }
    }

    acc += __shfl_xor(acc, 32, 64);
    if (lane < 32)
        agg[(size_t)wid * HD + 32 * half + c] = acc;
}

// Layer-3: channel-split agg fused with pool stage 1 (atomic into partial).
__global__ __launch_bounds__(256) void agg_pool_k(
    const unsigned short* __restrict__ h0, const unsigned short* __restrict__ h1,
    const float* __restrict__ dis, const int* __restrict__ offsets,
    const int* __restrict__ csr_src, const int* __restrict__ batch,
    float* __restrict__ partial, int n)
{
    __shared__ float rows[4 * 32];
    __shared__ int   gid[4];
    int t    = threadIdx.x;
    int lane = t & 63;
    int w    = t >> 6;
    int wid  = (blockIdx.x * blockDim.x + t) >> 6;
    int half = blockIdx.y;
    const unsigned short* __restrict__ tab = half ? h1 : h0;
    int c = lane & 31;
    int e = lane >> 5;

    // each wave inits exactly the slots it may later write (no cross-wave race)
    if (lane < 32) rows[w * 32 + lane] = 0.f;
    if (lane == 0) gid[w] = -1;

    if (wid < n) {
        float dn = dis[wid];
        float acc = 0.f;
        if (e == 0)
            acc = dn * dn * bf2f(tab[(size_t)wid * 32 + c]);
        int beg = offsets[wid], end = offsets[wid + 1];
        for (int base = beg; base < end; base += 64) {
            int m = min(64, end - base);
            int idx = 0;
            float dv = 0.f;
            if (lane < m) {
                idx = csr_src[base + lane];
                dv  = dis[idx];
            }
            int lim = m - 1;
            for (int j = 0; j < m; j += 16) {
                int rw[8];
                float h[8];
                #pragma unroll
                for (int u = 0; u < 8; ++u) {
                    int j2 = j + 2 * u;
                    int s0 = rdlane(idx, min(j2, lim));
                    int s1 = rdlane(idx, min(j2 + 1, lim));
                    rw[u] = e ? s1 : s0;
                }
                #pragma unroll
                for (int u = 0; u < 8; ++u)
                    h[u] = bf2f(tab[(size_t)rw[u] * 32 + c]);
                #pragma unroll
                for (int u = 0; u < 8; ++u) {
                    int j2 = j + 2 * u;
                    float w0 = (j2     < m) ? rdlanef(dv, min(j2, lim))     : 0.f;
                    float w1 = (j2 + 1 < m) ? rdlanef(dv, min(j2 + 1, lim)) : 0.f;
                    float wgt = e ? w1 : w0;
                    acc += dn * wgt * h[u];
                }
            }
        }
        acc += __shfl_xor(acc, 32, 64);
        if (lane < 32) rows[w * 32 + lane] = acc;
        if (lane == 0) gid[w] = batch[wid];
    }
    __syncthreads();

    if (t < 32) {
        int g0 = gid[0], g1 = gid[1], g2 = gid[2], g3 = gid[3];
        int slot = blockIdx.x & (PSUB - 1);
        int ch = 32 * half + t;
        if (g0 == g1 && g1 == g2 && g2 == g3 && g0 >= 0) {
            float v = rows[t] + rows[32 + t] + rows[64 + t] + rows[96 + t];
            atomicAdd(&partial[((size_t)g0 * PSUB + slot) * HD + ch], v);
        } else {
            if (g0 >= 0) atomicAdd(&partial[((size_t)g0 * PSUB + slot) * HD + ch], rows[t]);
            if (g1 >= 0) atomicAdd(&partial[((size_t)g1 * PSUB + slot) * HD + ch], rows[32 + t]);
            if (g2 >= 0) atomicAdd(&partial[((size_t)g2 * PSUB + slot) * HD + ch], rows[64 + t]);
            if (g3 >= 0) atomicAdd(&partial[((size_t)g3 * PSUB + slot) * HD + ch], rows[96 + t]);
        }
    }
}

// graph segment starts (batch is sorted)
__global__ void gstart_k(const int* __restrict__ batch, int* __restrict__ gstart, int n, int G)
{
    int g = blockIdx.x * blockDim.x + threadIdx.x;
    if (g > G) return;
    if (g == G) { gstart[g] = n; return; }
    int lo = 0, hi = n;
    while (lo < hi) { int m = (lo + hi) >> 1; if (batch[m] < g) lo = m + 1; else hi = m; }
    gstart[g] = lo;
}

// pooling stage 2: reduce partials, mean + b3, final linear
__global__ __launch_bounds__(64) void pool2_k(const float* __restrict__ partial,
    const int* __restrict__ gstart, const float* __restrict__ b3,
    const float* __restrict__ Wl, const float* __restrict__ bl,
    float* __restrict__ out, int O)
{
    __shared__ float pooled[HD];
    int g = blockIdx.x;
    int t = threadIdx.x;
    float sum = 0.0f;
    #pragma unroll
    for (int s = 0; s < PSUB; ++s)
        sum += partial[((size_t)g * PSUB + s) * HD + t];
    float cnt = (float)(gstart[g + 1] - gstart[g]);
    pooled[t] = sum / cnt + b3[t];
    __syncthreads();
    if (t < O) {
        float acc = bl[t];
        #pragma unroll
        for (int k = 0; k < HD; ++k) acc += pooled[k] * Wl[k * O + t];
        out[g * O + t] = acc;
    }
}

extern "C" void kernel_launch(void* const* d_in, const int* in_sizes, int n_in,
                              void* d_out, int out_size, void* d_ws, size_t ws_size,
                              hipStream_t stream)
{
    const float* x    = (const float*)d_in[0];
    const int*   ei   = (const int*)d_in[1];
    const int*   batch= (const int*)d_in[2];
    const float* W1   = (const float*)d_in[3];
    const float* b1   = (const float*)d_in[4];
    const float* W2   = (const float*)d_in[5];
    const float* b2   = (const float*)d_in[6];
    const float* W3   = (const float*)d_in[7];
    const float* b3   = (const float*)d_in[8];
    const float* Wl   = (const float*)d_in[9];
    const float* bl   = (const float*)d_in[10];
    float* out = (float*)d_out;

    const int N = in_sizes[0] / HD;
    const int E = in_sizes[1] / 2;
    const int O = in_sizes[10];
    const int G = out_size / O;

    const int* src = ei;
    const int* dst = ei + E;

    // ---- workspace layout (256 B aligned) ----
    char* p = (char*)d_ws;
    auto take = [&](size_t bytes) { char* r = p; p += (bytes + 255) & ~(size_t)255; return r; };
    int*   csr_src = (int*)  take((size_t)(E + 256) * 4);  // padded for over-read
    int*   offsets = (int*)  take((size_t)(N + 1) * 4);
    float* dis     = (float*)take((size_t)N * 4);
    int*   gstart  = (int*)  take((size_t)(G + 1) * 4);
    float* partial = (float*)take((size_t)G * PSUB * HD * 4);   // 256 KB
    float* aggF    = (float*)take((size_t)N * HD * 4);          // 12.8 MB (fp32 agg out)
    unsigned short* halfA0 = (unsigned short*)take((size_t)N * 32 * 2);  // 3.2 MB
    unsigned short* halfA1 = (unsigned short*)take((size_t)N * 32 * 2);  // 3.2 MB

    // aliases into regions not yet live during CSR build:
    int* hist    = (int*)aggF;                 // 1 MB
    int* scanned = hist + NBLK * NBKT;         // 1 MB
    int* tsum    = scanned + NBLK * NBKT;      // 4 KB
    int* pairs   = (int*)halfA0;               // E*4 = 3.2 MB (packed) — dead after build

    const int TB = 256;
    int chunk   = (E + NBLK - 1) / NBLK;
    int ntiles  = (NBLK * NBKT) / 256;
    int nb_gemm = (N + 63) / 64;
    int nb_agg  = (N * 64 + TB - 1) / TB;      // 4 nodes per block
    int nbuck   = (N + 127) / 128;
    dim3 agg_grid(nb_agg, 2);                  // y = channel half (y slowest)

    // zero the pooling accumulator (harness poisons d_ws each call)
    hipMemsetAsync(partial, 0, (size_t)G * PSUB * HD * 4, stream);

    // ---- CSR build (atomic-free counting sort, packed pairs) ----
    hist1_k<<<NBLK, TB, 0, stream>>>(dst, hist, E, chunk);
    scanA_k<<<ntiles, TB, 0, stream>>>(hist, tsum);
    scanB_k<<<1, 1024, 0, stream>>>(tsum, ntiles);
    scanC_k<<<ntiles, TB, 0, stream>>>(hist, tsum, scanned);
    append_k<<<NBLK, TB, 0, stream>>>(src, dst, scanned, pairs, E, chunk);
    bucket_csr_k<<<nbuck, TB, 0, stream>>>(pairs, scanned, offsets, dis, csr_src, N, E);
    gstart_k<<<1, 128, 0, stream>>>(batch, gstart, N, G);

    // ---- layer 1 ----
    gemm64_k<<<nb_gemm, TB, 0, stream>>>(x, nullptr, 0, W1, halfA0, halfA1, N);
    agg_csr_k<<<agg_grid, TB, 0, stream>>>(halfA0, halfA1, dis, offsets, csr_src, aggF, N);

    // ---- layer 2 ----
    gemm64_k<<<nb_gemm, TB, 0, stream>>>(aggF, b1, 1, W2, halfA0, halfA1, N);
    agg_csr_k<<<agg_grid, TB, 0, stream>>>(halfA0, halfA1, dis, offsets, csr_src, aggF, N);

    // ---- layer 3: gemm, then channel-split agg fused with pool stage 1 ----
    gemm64_k<<<nb_gemm, TB, 0, stream>>>(aggF, b2, 1, W3, halfA0, halfA1, N);
    agg_pool_k<<<agg_grid, TB, 0, stream>>>(halfA0, halfA1, dis, offsets, csr_src, batch, partial, N);

    // ---- pool stage 2 + final linear ----
    pool2_k<<<G, 64, 0, stream>>>(partial, gstart, b3, Wl, bl, out, O);
}

// Round 13
// 229.376 us; speedup vs baseline: 1.3980x; 1.3980x over previous
//
#include <hip/hip_runtime.h>

#define HD 64      // hidden/feature dim (D == H == 64)
#define PSUB 16    // partial slots per graph (pool accumulation spread)
#define NBLK 256   // histogram blocks (edge slices)
#define LOG_NBLK 8
#define NBKT 512   // dst buckets (bucket = dst >> 7, 128 nodes each; N <= 65536)

// ---- bf16 helpers (manual, RNE) ----
__device__ __forceinline__ unsigned short f2bf(float f) {
    union { float f; unsigned u; } v; v.f = f;
    unsigned r = v.u + 0x7FFF + ((v.u >> 16) & 1);
    return (unsigned short)(r >> 16);
}
__device__ __forceinline__ float bf2f(unsigned short h) {
    union { unsigned u; float f; } v; v.u = ((unsigned)h) << 16;
    return v.f;
}
__device__ __forceinline__ int rdlane(int v, int l) {
    return __builtin_amdgcn_readlane(v, l);
}

// ================= atomic-free bucketed CSR build =================

__global__ __launch_bounds__(256) void hist1_k(const int* __restrict__ dst,
                                               int* __restrict__ hist, int E, int chunk)
{
    __shared__ int lh[NBKT];
    int t = threadIdx.x;
    for (int i = t; i < NBKT; i += 256) lh[i] = 0;
    __syncthreads();
    int base = blockIdx.x * chunk;
    int end  = min(base + chunk, E);
    for (int i = base + t; i < end; i += 256)
        atomicAdd(&lh[dst[i] >> 7], 1);
    __syncthreads();
    for (int i = t; i < NBKT; i += 256)
        hist[blockIdx.x * NBKT + i] = lh[i];
}

// 2a) tile-reduce logical order l = bkt*NBLK + blk  (phys = blk*NBKT + bkt)
__global__ __launch_bounds__(256) void scanA_k(const int* __restrict__ hist,
                                               int* __restrict__ tsum)
{
    __shared__ int s[256];
    int t = threadIdx.x;
    int l = blockIdx.x * 256 + t;
    int phys = (l & (NBLK - 1)) * NBKT + (l >> LOG_NBLK);
    s[t] = hist[phys];
    __syncthreads();
    for (int off = 128; off > 0; off >>= 1) {
        if (t < off) s[t] += s[t + off];
        __syncthreads();
    }
    if (t == 0) tsum[blockIdx.x] = s[0];
}

// 2b) single block exclusive-scans tsum; ALSO computes gstart (graph segment
// starts via binary search over sorted batch) — merged to save a launch.
__global__ __launch_bounds__(1024) void scanB_k(int* __restrict__ tsum, int nb,
    const int* __restrict__ batch, int* __restrict__ gstart, int n, int G)
{
    __shared__ int s[1024];
    int t = threadIdx.x;
    int v = (t < nb) ? tsum[t] : 0;
    s[t] = v;
    __syncthreads();
    for (int off = 1; off < 1024; off <<= 1) {
        int u = (t >= off) ? s[t - off] : 0;
        __syncthreads();
        s[t] += u;
        __syncthreads();
    }
    if (t < nb) tsum[t] = s[t] - v;
    if (t <= G) {
        if (t == G) gstart[t] = n;
        else {
            int lo = 0, hi = n;
            while (lo < hi) { int m = (lo + hi) >> 1; if (batch[m] < t) lo = m + 1; else hi = m; }
            gstart[t] = lo;
        }
    }
}

__global__ __launch_bounds__(256) void scanC_k(const int* __restrict__ hist,
                                               const int* __restrict__ tsum,
                                               int* __restrict__ scanned)
{
    __shared__ int s[256];
    int t = threadIdx.x;
    int l = blockIdx.x * 256 + t;
    int phys = (l & (NBLK - 1)) * NBKT + (l >> LOG_NBLK);
    int own = hist[phys];
    s[t] = own;
    __syncthreads();
    for (int off = 1; off < 256; off <<= 1) {
        int u = (t >= off) ? s[t - off] : 0;
        __syncthreads();
        s[t] += u;
        __syncthreads();
    }
    scanned[l] = tsum[blockIdx.x] + s[t] - own;
}

// 3) bucket-sorted append of packed (src<<7 | dst&127); per-block private ranges
__global__ __launch_bounds__(256) void append_k(const int* __restrict__ src,
    const int* __restrict__ dst, const int* __restrict__ scanned,
    int* __restrict__ pairs, int E, int chunk)
{
    __shared__ int cur[NBKT];
    int t = threadIdx.x;
    int blk = blockIdx.x;
    for (int i = t; i < NBKT; i += 256) cur[i] = scanned[i * NBLK + blk];
    __syncthreads();
    int base = blk * chunk;
    int end  = min(base + chunk, E);
    for (int i = base + t; i < end; i += 256) {
        int s = src[i], d = dst[i];
        int p = atomicAdd(&cur[d >> 7], 1);
        pairs[p] = (s << 7) | (d & 127);
    }
}

// 4) per-bucket: node counts -> offsets/dis, then in-bucket scatter of csr_src
__global__ __launch_bounds__(256) void bucket_csr_k(const int* __restrict__ pairs,
    const int* __restrict__ scanned, int* __restrict__ offsets,
    float* __restrict__ dis, int* __restrict__ csr_src, int N, int E)
{
    __shared__ int cnt[128];
    __shared__ int sc[128];
    __shared__ int cur[128];
    int t = threadIdx.x;
    int b = blockIdx.x;
    int nodeBase = b * 128;
    int nNodes = min(128, N - nodeBase);
    int bBase = scanned[b * NBLK];
    int bEnd  = (b + 1 < NBKT) ? scanned[(b + 1) * NBLK] : E;

    if (t < 128) cnt[t] = 0;
    __syncthreads();
    for (int i = bBase + t; i < bEnd; i += 256)
        atomicAdd(&cnt[pairs[i] & 127], 1);
    __syncthreads();
    int myc = (t < 128) ? cnt[t] : 0;
    if (t < 128) sc[t] = myc;
    __syncthreads();
    for (int off = 1; off < 128; off <<= 1) {
        int u = (t < 128 && t >= off) ? sc[t - off] : 0;
        __syncthreads();
        if (t < 128) sc[t] += u;
        __syncthreads();
    }
    if (t < 128) {
        int excl = sc[t] - myc;
        cur[t] = excl;
        if (t < nNodes) {
            offsets[nodeBase + t] = bBase + excl;
            dis[nodeBase + t] = rsqrtf(1.0f + (float)myc);
        }
    }
    if (t == 0 && b == gridDim.x - 1) offsets[N] = E;
    __syncthreads();
    for (int i = bBase + t; i < bEnd; i += 256) {
        int pk = pairs[i];
        int pos = bBase + atomicAdd(&cur[pk & 127], 1);
        csr_src[pos] = ((unsigned)pk) >> 7;
    }
}

// ================= layers =================

// register-tiled 64x64 GEMM, bf16 output PREMULTIPLIED by dis[row]:
// outb[r,c] = f2bf(dis[r] * (act(in+b_prev) @ W)[r,c]).  Row n of outb zeroed.
__global__ __launch_bounds__(256) void gemm64_k(
    const float* __restrict__ in, const float* __restrict__ b_prev, int relu_prev,
    const float* __restrict__ W, const float* __restrict__ dis,
    unsigned short* __restrict__ outb, int n)
{
    __shared__ float HsT[HD][68];
    __shared__ float Ws[HD][HD];
    int t = threadIdx.x;
    int rowBase = blockIdx.x * 64;

    for (int i = t; i < HD * HD / 4; i += 256)
        ((float4*)Ws)[i] = ((const float4*)W)[i];

    if (blockIdx.x == 0 && t < 64)   // zero pad-row n (gather target for tails)
        outb[(size_t)n * HD + t] = 0;

    {
        int k0 = (t & 15) * 4;
        float4 bb = make_float4(0.f, 0.f, 0.f, 0.f);
        if (b_prev) bb = *(const float4*)&b_prev[k0];
        for (int it = 0; it < 4; ++it) {
            int r = (t >> 4) + it * 16;
            int row = rowBase + r;
            float4 v = make_float4(0.f, 0.f, 0.f, 0.f);
            if (row < n) {
                v = *(const float4*)&in[(size_t)row * HD + k0];
                v.x += bb.x; v.y += bb.y; v.z += bb.z; v.w += bb.w;
                if (relu_prev) {
                    v.x = fmaxf(v.x, 0.f); v.y = fmaxf(v.y, 0.f);
                    v.z = fmaxf(v.z, 0.f); v.w = fmaxf(v.w, 0.f);
                }
            }
            HsT[k0 + 0][r] = v.x;
            HsT[k0 + 1][r] = v.y;
            HsT[k0 + 2][r] = v.z;
            HsT[k0 + 3][r] = v.w;
        }
    }
    __syncthreads();

    int c4 = (t & 15) * 4;
    int r4 = (t >> 4) * 4;
    float acc[4][4];
    #pragma unroll
    for (int i = 0; i < 4; ++i)
        #pragma unroll
        for (int j = 0; j < 4; ++j) acc[i][j] = 0.f;

    #pragma unroll 8
    for (int k = 0; k < HD; ++k) {
        float4 a = *(const float4*)&HsT[k][r4];
        float4 b = *(const float4*)&Ws[k][c4];
        acc[0][0] += a.x * b.x; acc[0][1] += a.x * b.y; acc[0][2] += a.x * b.z; acc[0][3] += a.x * b.w;
        acc[1][0] += a.y * b.x; acc[1][1] += a.y * b.y; acc[1][2] += a.y * b.z; acc[1][3] += a.y * b.w;
        acc[2][0] += a.z * b.x; acc[2][1] += a.z * b.y; acc[2][2] += a.z * b.z; acc[2][3] += a.z * b.w;
        acc[3][0] += a.w * b.x; acc[3][1] += a.w * b.y; acc[3][2] += a.w * b.z; acc[3][3] += a.w * b.w;
    }

    #pragma unroll
    for (int i = 0; i < 4; ++i) {
        int row = rowBase + r4 + i;
        if (row < n) {
            float ds = dis[row];
            ushort4 o;
            o.x = f2bf(ds * acc[i][0]); o.y = f2bf(ds * acc[i][1]);
            o.z = f2bf(ds * acc[i][2]); o.w = f2bf(ds * acc[i][3]);
            *(ushort4*)&outb[(size_t)row * HD + c4] = o;
        }
    }
}

// CSR gather-aggregate over dis-premultiplied bf16 table: pure adds.
// agg[n] = dis[n] * (h'[n] + sum h'[src]); tail lanes point at zero row n.
__global__ __launch_bounds__(256) void agg_csr_k(const unsigned short* __restrict__ hwb,
    const float* __restrict__ dis, const int* __restrict__ offsets,
    const int* __restrict__ csr_src, float* __restrict__ agg, int n)
{
    int wid  = (blockIdx.x * blockDim.x + threadIdx.x) >> 6;
    int lane = threadIdx.x & 63;
    if (wid >= n) return;
    float acc = bf2f(hwb[(size_t)wid * HD + lane]);   // self-loop (pre-dn)
    int beg = offsets[wid], end = offsets[wid + 1];

    for (int base = beg; base < end; base += 64) {
        int m = min(64, end - base);
        int idx = (lane < m) ? csr_src[base + lane] : n;   // pad -> zero row
        for (int j = 0; j < m; j += 16) {
            int ss[16];
            float h[16];
            #pragma unroll
            for (int u = 0; u < 16; ++u)
                ss[u] = rdlane(idx, j + u);                // j+u < 64 always
            #pragma unroll
            for (int u = 0; u < 16; ++u)
                h[u] = bf2f(hwb[(size_t)ss[u] * HD + lane]);  // 16 in flight
            #pragma unroll
            for (int u = 0; u < 16; ++u)
                acc += h[u];
        }
    }
    agg[(size_t)wid * HD + lane] = dis[wid] * acc;
}

// Layer-3 agg fused with pool stage 1 (atomic into partial[g][slot][64]).
__global__ __launch_bounds__(256) void agg_pool_k(const unsigned short* __restrict__ hwb,
    const float* __restrict__ dis, const int* __restrict__ offsets,
    const int* __restrict__ csr_src, const int* __restrict__ batch,
    float* __restrict__ partial, int n)
{
    __shared__ float rows[4 * HD];
    __shared__ int   gid[4];
    int t    = threadIdx.x;
    int lane = t & 63;
    int w    = t >> 6;
    int wid  = (blockIdx.x * blockDim.x + t) >> 6;

    rows[t] = 0.f;
    if (t < 4) gid[t] = -1;

    if (wid < n) {
        float acc = bf2f(hwb[(size_t)wid * HD + lane]);
        int beg = offsets[wid], end = offsets[wid + 1];
        for (int base = beg; base < end; base += 64) {
            int m = min(64, end - base);
            int idx = (lane < m) ? csr_src[base + lane] : n;
            for (int j = 0; j < m; j += 16) {
                int ss[16];
                float h[16];
                #pragma unroll
                for (int u = 0; u < 16; ++u)
                    ss[u] = rdlane(idx, j + u);
                #pragma unroll
                for (int u = 0; u < 16; ++u)
                    h[u] = bf2f(hwb[(size_t)ss[u] * HD + lane]);
                #pragma unroll
                for (int u = 0; u < 16; ++u)
                    acc += h[u];
            }
        }
        rows[w * HD + lane] = dis[wid] * acc;
        if (lane == 0) gid[w] = batch[wid];
    }
    __syncthreads();

    if (t < HD) {
        int g0 = gid[0], g1 = gid[1], g2 = gid[2], g3 = gid[3];
        int slot = blockIdx.x & (PSUB - 1);
        if (g0 == g1 && g1 == g2 && g2 == g3 && g0 >= 0) {
            float v = rows[t] + rows[HD + t] + rows[2 * HD + t] + rows[3 * HD + t];
            atomicAdd(&partial[((size_t)g0 * PSUB + slot) * HD + t], v);
        } else {
            if (g0 >= 0) atomicAdd(&partial[((size_t)g0 * PSUB + slot) * HD + t], rows[t]);
            if (g1 >= 0) atomicAdd(&partial[((size_t)g1 * PSUB + slot) * HD + t], rows[HD + t]);
            if (g2 >= 0) atomicAdd(&partial[((size_t)g2 * PSUB + slot) * HD + t], rows[2 * HD + t]);
            if (g3 >= 0) atomicAdd(&partial[((size_t)g3 * PSUB + slot) * HD + t], rows[3 * HD + t]);
        }
    }
}

// pooling stage 2: reduce partials, mean + b3, final linear
__global__ __launch_bounds__(64) void pool2_k(const float* __restrict__ partial,
    const int* __restrict__ gstart, const float* __restrict__ b3,
    const float* __restrict__ Wl, const float* __restrict__ bl,
    float* __restrict__ out, int O)
{
    __shared__ float pooled[HD];
    int g = blockIdx.x;
    int t = threadIdx.x;
    float sum = 0.0f;
    #pragma unroll
    for (int s = 0; s < PSUB; ++s)
        sum += partial[((size_t)g * PSUB + s) * HD + t];
    float cnt = (float)(gstart[g + 1] - gstart[g]);
    pooled[t] = sum / cnt + b3[t];
    __syncthreads();
    if (t < O) {
        float acc = bl[t];
        #pragma unroll
        for (int k = 0; k < HD; ++k) acc += pooled[k] * Wl[k * O + t];
        out[g * O + t] = acc;
    }
}

extern "C" void kernel_launch(void* const* d_in, const int* in_sizes, int n_in,
                              void* d_out, int out_size, void* d_ws, size_t ws_size,
                              hipStream_t stream)
{
    const float* x    = (const float*)d_in[0];
    const int*   ei   = (const int*)d_in[1];
    const int*   batch= (const int*)d_in[2];
    const float* W1   = (const float*)d_in[3];
    const float* b1   = (const float*)d_in[4];
    const float* W2   = (const float*)d_in[5];
    const float* b2   = (const float*)d_in[6];
    const float* W3   = (const float*)d_in[7];
    const float* b3   = (const float*)d_in[8];
    const float* Wl   = (const float*)d_in[9];
    const float* bl   = (const float*)d_in[10];
    float* out = (float*)d_out;

    const int N = in_sizes[0] / HD;
    const int E = in_sizes[1] / 2;
    const int O = in_sizes[10];
    const int G = out_size / O;

    const int* src = ei;
    const int* dst = ei + E;

    // ---- workspace layout (256 B aligned) ----
    char* p = (char*)d_ws;
    auto take = [&](size_t bytes) { char* r = p; p += (bytes + 255) & ~(size_t)255; return r; };
    int*   csr_src = (int*)  take((size_t)(E + 256) * 4);  // padded for over-read
    int*   offsets = (int*)  take((size_t)(N + 1) * 4);
    float* dis     = (float*)take((size_t)N * 4);
    int*   gstart  = (int*)  take((size_t)(G + 1) * 4);
    float* partial = (float*)take((size_t)G * PSUB * HD * 4);   // 256 KB
    float* aggF    = (float*)take((size_t)N * HD * 4);          // 12.8 MB
    unsigned short* hwb = (unsigned short*)take((size_t)(N + 1) * HD * 2);  // 6.4 MB (+zero row)

    // aliases into regions not yet live during CSR build:
    int* hist    = (int*)aggF;                 // NBLK*NBKT*4 = 512 KB
    int* scanned = hist + NBLK * NBKT;         // 512 KB
    int* tsum    = scanned + NBLK * NBKT;      // 2 KB
    int* pairs   = (int*)hwb;                  // E*4 = 3.2 MB (packed)

    const int TB = 256;
    int chunk   = (E + NBLK - 1) / NBLK;
    int ntiles  = (NBLK * NBKT) / 256;         // 512
    int nb_gemm = (N + 63) / 64;
    int nb_agg  = (N * 64 + TB - 1) / TB;
    int nbuck   = (N + 127) / 128;

    // zero the pooling accumulator (harness poisons d_ws each call)
    hipMemsetAsync(partial, 0, (size_t)G * PSUB * HD * 4, stream);

    // ---- CSR build (atomic-free counting sort, packed pairs) ----
    hist1_k<<<NBLK, TB, 0, stream>>>(dst, hist, E, chunk);
    scanA_k<<<ntiles, TB, 0, stream>>>(hist, tsum);
    scanB_k<<<1, 1024, 0, stream>>>(tsum, ntiles, batch, gstart, N, G);
    scanC_k<<<ntiles, TB, 0, stream>>>(hist, tsum, scanned);
    append_k<<<NBLK, TB, 0, stream>>>(src, dst, scanned, pairs, E, chunk);
    bucket_csr_k<<<nbuck, TB, 0, stream>>>(pairs, scanned, offsets, dis, csr_src, N, E);

    // ---- layer 1 ----
    gemm64_k<<<nb_gemm, TB, 0, stream>>>(x, nullptr, 0, W1, dis, hwb, N);
    agg_csr_k<<<nb_agg, TB, 0, stream>>>(hwb, dis, offsets, csr_src, aggF, N);

    // ---- layer 2 ----
    gemm64_k<<<nb_gemm, TB, 0, stream>>>(aggF, b1, 1, W2, dis, hwb, N);
    agg_csr_k<<<nb_agg, TB, 0, stream>>>(hwb, dis, offsets, csr_src, aggF, N);

    // ---- layer 3: gemm, then agg fused with pool stage 1 ----
    gemm64_k<<<nb_gemm, TB, 0, stream>>>(aggF, b2, 1, W3, dis, hwb, N);
    agg_pool_k<<<nb_agg, TB, 0, stream>>>(hwb, dis, offsets, csr_src, batch, partial, N);

    // ---- pool stage 2 + final linear ----
    pool2_k<<<G, 64, 0, stream>>>(partial, gstart, b3, Wl, bl, out, O);
}